// Round 5
// baseline (34.272 us; speedup 1.0000x reference)
//
#include <hip/hip_runtime.h>

// SSIM map: refl-pad(1) + 3x3 avg-pool stencil, B=16 C=3 H=512 W=512 fp32.
// Memory-bound: 151 MB compulsory HBM traffic -> ~24 us floor at 6.3 TB/s.

#define HH 512
#define WW 512
#define ROWS 32          // rows per thread; grid.y = HH/ROWS
#define SSIM_C1 1e-4f    // 0.01^2
#define SSIM_C2 9e-4f    // 0.03^2

__global__ __launch_bounds__(256) void ssim_kernel(const float* __restrict__ x,
                                                   const float* __restrict__ y,
                                                   float* __restrict__ out) {
    const int col   = blockIdx.x * 256 + threadIdx.x;   // 0..511
    const int row0  = blockIdx.y * ROWS;
    const size_t po = (size_t)blockIdx.z * (size_t)(HH * WW);
    const float* xp = x + po;
    const float* yp = y + po;
    float* op       = out + po;

    // reflection-pad(1) column neighbors
    const int cl = (col == 0)      ? 1      : col - 1;
    const int cr = (col == WW - 1) ? WW - 2 : col + 1;

    // 3-deep sliding window of horizontal row-sums for 5 quantities.
    float sx0, sy0, sxx0, syy0, sxy0;
    float sx1, sy1, sxx1, syy1, sxy1;
    float sx2, sy2, sxx2, syy2, sxy2;

#define LOADROW(r, SX, SY, SXX, SYY, SXY) do {                      \
    int rr_ = (r) < 0 ? 1 : ((r) >= HH ? HH - 2 : (r));             \
    const float* xr_ = xp + rr_ * WW;                               \
    const float* yr_ = yp + rr_ * WW;                               \
    float xl_ = xr_[cl], xc_ = xr_[col], xv_ = xr_[cr];             \
    float yl_ = yr_[cl], yc_ = yr_[col], yv_ = yr_[cr];             \
    SX  = xl_ + xc_ + xv_;                                          \
    SY  = yl_ + yc_ + yv_;                                          \
    SXX = xl_*xl_ + xc_*xc_ + xv_*xv_;                              \
    SYY = yl_*yl_ + yc_*yc_ + yv_*yv_;                              \
    SXY = xl_*yl_ + xc_*yc_ + xv_*yv_;                              \
} while (0)

    // Prime rows row0-1 (reflected) and row0.
    LOADROW(row0 - 1, sx0, sy0, sxx0, syy0, sxy0);
    LOADROW(row0,     sx1, sy1, sxx1, syy1, sxy1);

    const float inv9 = 1.0f / 9.0f;

    #pragma unroll 4
    for (int i = 0; i < ROWS; ++i) {
        const int r = row0 + i;
        LOADROW(r + 1, sx2, sy2, sxx2, syy2, sxy2);

        const float sx  = sx0  + sx1  + sx2;
        const float sy  = sy0  + sy1  + sy2;
        const float sxx = sxx0 + sxx1 + sxx2;
        const float syy = syy0 + syy1 + syy2;
        const float sxy = sxy0 + sxy1 + sxy2;

        const float mux   = sx * inv9;
        const float muy   = sy * inv9;
        const float sigx  = sxx * inv9 - mux * mux;
        const float sigy  = syy * inv9 - muy * muy;
        const float sigxy = sxy * inv9 - mux * muy;

        const float n = (2.0f * mux * muy + SSIM_C1) * (2.0f * sigxy + SSIM_C2);
        const float d = (mux * mux + muy * muy + SSIM_C1) * (sigx + sigy + SSIM_C2);
        float v = (1.0f - n / (d + 1e-8f)) * 0.5f;
        v = fminf(fmaxf(v, 0.0f), 1.0f);

        op[(size_t)r * WW + col] = v;

        // slide window down one row (scalar shift -> SSA-renamed, no scratch)
        sx0 = sx1;  sy0 = sy1;  sxx0 = sxx1;  syy0 = syy1;  sxy0 = sxy1;
        sx1 = sx2;  sy1 = sy2;  sxx1 = sxx2;  syy1 = syy2;  sxy1 = sxy2;
    }
#undef LOADROW
}

extern "C" void kernel_launch(void* const* d_in, const int* in_sizes, int n_in,
                              void* d_out, int out_size, void* d_ws, size_t ws_size,
                              hipStream_t stream) {
    const float* x = (const float*)d_in[0];
    const float* y = (const float*)d_in[1];
    float* out     = (float*)d_out;

    // B*C = 48 planes of 512x512
    dim3 block(256, 1, 1);
    dim3 grid(WW / 256, HH / ROWS, 48);   // (2, 16, 48) = 1536 blocks
    ssim_kernel<<<grid, block, 0, stream>>>(x, y, out);
}